// Round 15
// baseline (993.079 us; speedup 1.0000x reference)
//
#include <hip/hip_runtime.h>

typedef unsigned short u16;
typedef __attribute__((ext_vector_type(8))) short short8;
typedef __attribute__((ext_vector_type(4))) float f32x4;
typedef __attribute__((ext_vector_type(4))) u16 ushort4v;
typedef __attribute__((ext_vector_type(8))) u16 ushort8v;

#define DIM 2048
#define HID 5632
#define F2  11264
#define TTOT 8192

#define GLD(g, l) __builtin_amdgcn_global_load_lds(                       \
    (const __attribute__((address_space(1))) void*)(g),                   \
    (__attribute__((address_space(3))) void*)(l), 16, 0, 0)

__device__ __forceinline__ u16 f2bf(float f) {
  unsigned int u = __builtin_bit_cast(unsigned int, f);
  u += 0x7FFFu + ((u >> 16) & 1u);   // round-to-nearest-even (finite values)
  return (u16)(u >> 16);
}

// ---- weight conversion: w13 fp32 -> bf16, rows PERMUTED so (x1,x3) pairs are
// 16-col groups: new row r: b=r>>5, i=r&31; orig = i<16 ? b*16+i : HID+b*16+(i-16)
__global__ __launch_bounds__(256) void conv_w13(const float* __restrict__ w,
                                                u16* __restrict__ o) {
  int idx = blockIdx.x * 256 + threadIdx.x;          // 0 .. F2*DIM/4-1
  int rnew = idx >> 9;                               // DIM/4 = 512 float4/row
  int dc = (idx & 511) << 2;
  int b = rnew >> 5, ii = rnew & 31;
  int orig = (ii < 16) ? (b * 16 + ii) : (HID + b * 16 + (ii - 16));
  float4 v = *reinterpret_cast<const float4*>(w + (size_t)orig * DIM + dc);
  ushort4v q = {f2bf(v.x), f2bf(v.y), f2bf(v.z), f2bf(v.w)};
  *reinterpret_cast<ushort4v*>(o + (size_t)rnew * DIM + dc) = q;
}

__global__ __launch_bounds__(256) void conv_w2(const float* __restrict__ w,
                                               u16* __restrict__ o) {
  size_t e = ((size_t)blockIdx.x * 256 + threadIdx.x) * 4;
  float4 v = *reinterpret_cast<const float4*>(w + e);
  ushort4v q = {f2bf(v.x), f2bf(v.y), f2bf(v.z), f2bf(v.w)};
  *reinterpret_cast<ushort4v*>(o + e) = q;
}

// ---- per-token quant of x: q = rint(x*s) as bf16 (exact ints), scale = max/127
__global__ __launch_bounds__(256) void quant_x(const float* __restrict__ x,
                                               u16* __restrict__ q,
                                               float* __restrict__ scale) {
  const int t = blockIdx.x;
  const float* xr = x + (size_t)t * DIM;
  const int tid = threadIdx.x;
  float4 a = *reinterpret_cast<const float4*>(xr + tid * 8);
  float4 b = *reinterpret_cast<const float4*>(xr + tid * 8 + 4);
  float v[8] = {a.x, a.y, a.z, a.w, b.x, b.y, b.z, b.w};
  float m = 0.f;
#pragma unroll
  for (int i = 0; i < 8; ++i) m = fmaxf(m, fabsf(v[i]));
#pragma unroll
  for (int off = 32; off; off >>= 1) m = fmaxf(m, __shfl_xor(m, off));
  __shared__ float red[4];
  if ((tid & 63) == 0) red[tid >> 6] = m;
  __syncthreads();
  m = fmaxf(fmaxf(red[0], red[1]), fmaxf(red[2], red[3]));
  m = fmaxf(m, 1e-5f);
  float s = 127.0f / m;
  if (tid == 0) scale[t] = m / 127.0f;
  ushort8v o;
#pragma unroll
  for (int i = 0; i < 8; ++i) {
    float r = fminf(fmaxf(rintf(v[i] * s), -128.f), 127.f);
    o[i] = f2bf(r);
  }
  *reinterpret_cast<ushort8v*>(q + (size_t)t * DIM + tid * 8) = o;
}

// ---- gated row -> rmsnorm -> quant (bf16 ints) + scale
__global__ __launch_bounds__(256) void gate_nq(const float* __restrict__ G,
                                               const float* __restrict__ nw,
                                               u16* __restrict__ q2,
                                               float* __restrict__ s2) {
  const int t = blockIdx.x;
  const float* gr = G + (size_t)t * HID;
  const int tid = threadIdx.x;
  float4 vv[6];
  float ss = 0.f, mx = 0.f;
#pragma unroll
  for (int k = 0; k < 6; ++k) {
    int i = tid + k * 256;
    if (i < 1408) {
      float4 v = *reinterpret_cast<const float4*>(gr + i * 4);
      float4 w4 = *reinterpret_cast<const float4*>(nw + i * 4);
      vv[k] = v;
      ss += v.x * v.x + v.y * v.y + v.z * v.z + v.w * v.w;
      mx = fmaxf(mx, fmaxf(fmaxf(fabsf(v.x * w4.x), fabsf(v.y * w4.y)),
                           fmaxf(fabsf(v.z * w4.z), fabsf(v.w * w4.w))));
    }
  }
#pragma unroll
  for (int off = 32; off; off >>= 1) {
    ss += __shfl_xor(ss, off);
    mx = fmaxf(mx, __shfl_xor(mx, off));
  }
  __shared__ float rs[4], rm[4];
  if ((tid & 63) == 0) { rs[tid >> 6] = ss; rm[tid >> 6] = mx; }
  __syncthreads();
  ss = rs[0] + rs[1] + rs[2] + rs[3];
  mx = fmaxf(fmaxf(rm[0], rm[1]), fmaxf(rm[2], rm[3]));
  float rinv = 1.0f / sqrtf(ss * (1.0f / 5632.0f) + 1e-5f);
  float mi = fmaxf(mx * rinv, 1e-5f);
  float s = 127.0f / mi;
  if (tid == 0) s2[t] = mi / 127.0f;
  float fs = rinv * s;
#pragma unroll
  for (int k = 0; k < 6; ++k) {
    int i = tid + k * 256;
    if (i < 1408) {
      float4 v = vv[k];
      float4 w4 = *reinterpret_cast<const float4*>(nw + i * 4);
      ushort4v o;
      o.x = f2bf(fminf(fmaxf(rintf(v.x * w4.x * fs), -128.f), 127.f));
      o.y = f2bf(fminf(fmaxf(rintf(v.y * w4.y * fs), -128.f), 127.f));
      o.z = f2bf(fminf(fmaxf(rintf(v.z * w4.z * fs), -128.f), 127.f));
      o.w = f2bf(fminf(fmaxf(rintf(v.w * w4.w * fs), -128.f), 127.f));
      *reinterpret_cast<ushort4v*>(q2 + (size_t)t * HID + i * 4) = o;
    }
  }
}

// ============================================================================
// 256x256 GEMM, A-in-LDS + B-DIRECT-FROM-GLOBAL (cuts the LDS pipe ~35%):
// Cycle model (r14 post-mortem): per K-tile/CU, LDS was 2816 cyc (192 b128
// reads + 64KB writes) vs per-SIMD MFMA 2368; barrier lockstep => SUM = 5184
// ~= measured 5138. B elements are read only 2x and the B panels (46/23 MB)
// are L3-resident + L2-shared across the supertile -> load B fragments
// straight global->VGPR (same regs ds_read used to fill; zero VGPR delta).
// New LDS: A only = 128KB reads + 32KB writes ~= 1800 cyc/K-tile.
// Phase (2 per K-tile, BK=64):
//   phA: [stage A-kk1[u+1]->db^1]; load B kk0+kk1 (8 global dwordx4);
//        ds_read A kk0 (8); MFMA kk0 x32; barrier
//   phB: [stage A-kk0[u+2]->db]; ds_read A kk1 (8); MFMA kk1 x32; barrier
// Waits are COMPILER-MANAGED: hipcc sees the GLD builtins + B derefs and
// emits counted vmcnt before each MFMA group; those waits drain the older
// stage-GLDs (audited: every staged half drains >=2 barriers before its
// first ds_read; every stage-overwrite lands >=1 barrier after its region's
// last read). Manual vmcnt only in the prologue. Per-acc K order unchanged
// -> bit-identical output.
// LDS 64KB: [db][kk][256 rows][32 u16]; row r chunk slot = q^((r>>1)&3)
// (both-sides permutation; measured 0 bank conflicts). 512 thr = 8 waves
// (2M x 4N); per-wave 128x64. PANEL supertiling kept (FETCH 383->145 MB).
// GATE=1: gated epilogue over interleaved-w13 n-pairs, C is [M,N/2].
// ============================================================================
template <int GATE, int N, int K, int Ntiles>
__global__ __launch_bounds__(512, 2) void gemm8(
    const u16* __restrict__ A, const u16* __restrict__ B,
    const float* __restrict__ rowscale, float* __restrict__ C, int panel) {
  __shared__ __attribute__((aligned(16))) u16 lds[2][2][256 * 32];
  constexpr int NT = K >> 6;            // even: 32 (K=2048), 88 (K=5632)
  const int nwg = gridDim.x;
  const int orig = blockIdx.x;
  const int qq = nwg >> 3, rr = nwg & 7, xcd = orig & 7, sidx = orig >> 3;
  const int wg = (xcd < rr ? xcd * (qq + 1) : rr * (qq + 1) + (xcd - rr) * qq) + sidx;
  const int stripe = panel * Ntiles;
  const int mt = (wg / stripe) * panel + (wg % panel);
  const int nt = (wg % stripe) / panel;

  const int tid = threadIdx.x;
  const int wid = tid >> 6, lane = tid & 63;
  const int wm = wid >> 2, wn = wid & 3;
  const int c16 = lane & 15, q4 = lane >> 4;
  const int rA_base = wm * 128 + c16;
  const int caf = (q4 ^ ((lane >> 1) & 3)) << 3;  // chunk slot q4^((row>>1)&3)

  // A staging: row = tid>>2 (4 lanes/row, 64-B contiguous global segments),
  // source chunk = (tid&3) ^ ((row>>1)&3)  [inverse of the slot permutation]
  const int sr = tid >> 2;
  const int scol = ((tid & 3) ^ ((tid >> 3) & 3)) << 3;
  const u16* Ar = A + ((size_t)mt * 256 + sr) * K + scol;
  constexpr size_t rstep = (size_t)128 * K;

  // B fragments read directly from global: lane (c16,q4) of wave-col wn reads
  // row nt*256 + wn*64 + n*16 + c16, k = u*64 + kk*32 + q4*8 (8 bf16 = 16B).
  const u16* Bg = B + ((size_t)(nt * 256 + wn * 64 + c16)) * K + q4 * 8;

  f32x4 acc[8][4];
#pragma unroll
  for (int m = 0; m < 8; ++m)
#pragma unroll
    for (int n = 0; n < 4; ++n) acc[m][n] = f32x4{0.f, 0.f, 0.f, 0.f};

#define STAGE(KK, T, BUF)                                                     \
  {                                                                           \
    const u16* g = Ar + (T) * 64 + (KK) * 32;                                 \
    u16* l = &lds[BUF][KK][wid << 9];                                         \
    GLD(g, l);                                                                \
    GLD(g + rstep, l + 4096);                                                 \
  }
#define LDA(DB, KK, MH, AF)                                                   \
  _Pragma("unroll") for (int m = 0; m < 4; ++m)                               \
      AF[m] = *reinterpret_cast<const short8*>(                               \
          &lds[DB][KK][(rA_base + ((MH) * 4 + m) * 16) * 32 + caf]);
#define LDBG(U, KK, BF)                                                       \
  _Pragma("unroll") for (int n = 0; n < 4; ++n)                               \
      BF[n] = *reinterpret_cast<const short8*>(                               \
          Bg + (size_t)n * 16 * K + (U) * 64 + (KK) * 32);
#define MFMA32(AF0, AF1, BF)                                                  \
  __builtin_amdgcn_s_setprio(1);                                              \
  _Pragma("unroll") for (int m = 0; m < 4; ++m)                               \
      _Pragma("unroll") for (int n = 0; n < 4; ++n)                           \
          acc[m][n] = __builtin_amdgcn_mfma_f32_16x16x32_bf16(                \
              AF0[m], BF[n], acc[m][n], 0, 0, 0);                             \
  _Pragma("unroll") for (int m = 0; m < 4; ++m)                               \
      _Pragma("unroll") for (int n = 0; n < 4; ++n)                           \
          acc[4 + m][n] = __builtin_amdgcn_mfma_f32_16x16x32_bf16(            \
              AF1[m], BF[n], acc[4 + m][n], 0, 0, 0);                         \
  __builtin_amdgcn_s_setprio(0);                                              \
  __builtin_amdgcn_sched_barrier(0);
#define BARR asm volatile("s_barrier" ::: "memory")
#define VMC(NN) asm volatile("s_waitcnt vmcnt(" #NN ")" ::: "memory")

// One K-tile = 2 phases; A-stage at top; B loaded (both kk) at phA top.
#define KT2(DB, U, STGA, STGB)                                                \
  {                                                                           \
    short8 af0[4], af1[4], bk0[4], bk1[4];                                    \
    /* phase A: kk0 */                                                        \
    if (STGA) { STAGE(1, (U) + 1, (DB) ^ 1) }                                 \
    LDBG((U), 0, bk0)                                                         \
    LDBG((U), 1, bk1)                                                         \
    LDA(DB, 0, 0, af0)                                                        \
    LDA(DB, 0, 1, af1)                                                        \
    MFMA32(af0, af1, bk0)                                                     \
    BARR;                                                                     \
    /* phase B: kk1 */                                                        \
    if (STGB) { STAGE(0, (U) + 2, DB) }                                       \
    LDA(DB, 1, 0, af0)                                                        \
    LDA(DB, 1, 1, af1)                                                        \
    MFMA32(af0, af1, bk1)                                                     \
    BARR;                                                                     \
  }

  // prologue: A tile0 (kk0,kk1)->buf0 (4 GLD), A-kk0[1]->buf1 (2 GLD);
  // vmcnt(2) -> tile0 resident (4 oldest complete).
  STAGE(0, 0, 0) STAGE(1, 0, 0)
  STAGE(0, 1, 1)
  VMC(2);
  BARR;

#pragma unroll 1
  for (int u = 0; u < NT - 2; u += 2) {
    KT2(0, u, 1, 1)
    KT2(1, u + 1, 1, 1)
  }
  // tail: tile NT-2 stages A-kk1[NT-1] only; tile NT-1 stage-free.
  KT2(0, NT - 2, 1, 0)
  KT2(1, NT - 1, 0, 0)

  // ---- epilogue
  const int mbase0 = mt * 256 + wm * 128;
  if constexpr (GATE == 0) {
#pragma unroll
    for (int m = 0; m < 8; ++m) {
#pragma unroll
      for (int j = 0; j < 4; ++j) {
        const int row = mbase0 + m * 16 + q4 * 4 + j;
        const float sc = rowscale[row];
        float* crow = C + (size_t)row * N + nt * 256 + wn * 64 + c16;
#pragma unroll
        for (int n = 0; n < 4; ++n) crow[n * 16] = acc[m][n][j] * sc;
      }
    }
  } else {
    constexpr int H = N >> 1;
    const int gbase = (nt * 256 + wn * 64) >> 1;
#pragma unroll
    for (int m = 0; m < 8; ++m) {
#pragma unroll
      for (int j = 0; j < 4; ++j) {
        const int row = mbase0 + m * 16 + q4 * 4 + j;
        const float sc = rowscale[row];
        const float s3 = sc * sc * sc;
        float* grow = C + (size_t)row * H + gbase + c16;
#pragma unroll
        for (int p = 0; p < 2; ++p) {
          float a1 = acc[m][2 * p][j];
          float a3 = acc[m][2 * p + 1][j];
          float rl = fmaxf(a1, 0.f);
          grow[p * 16] = rl * rl * a3 * s3;
        }
      }
    }
  }
}

extern "C" void kernel_launch(void* const* d_in, const int* in_sizes, int n_in,
                              void* d_out, int out_size, void* d_ws, size_t ws_size,
                              hipStream_t stream) {
  const float* x = (const float*)d_in[0];
  const float* w13 = (const float*)d_in[1];
  const float* w2 = (const float*)d_in[2];
  const float* nw = (const float*)d_in[3];
  float* out = (float*)d_out;

  char* p = (char*)d_ws;
  u16* w13p = (u16*)p; p += (size_t)F2 * DIM * 2;
  u16* w2b = (u16*)p;  p += (size_t)DIM * HID * 2;
  u16* q2f = (u16*)p;  p += (size_t)TTOT * HID * 2;
  float* s2f = (float*)p; p += (size_t)TTOT * 4;
  const size_t fixed = (size_t)F2 * DIM * 2 + (size_t)DIM * HID * 2 +
                       (size_t)TTOT * HID * 2 + (size_t)TTOT * 4;
  const size_t perTok = (size_t)DIM * 2 + (size_t)HID * 4 + 8;
  int Tc = TTOT;
  while (Tc > 256 && fixed + (size_t)Tc * perTok > ws_size) Tc >>= 1;
  u16* q1 = (u16*)p;        p += (size_t)Tc * DIM * 2;
  float* gated = (float*)p; p += (size_t)Tc * HID * 4;
  float* s1 = (float*)p;

  conv_w13<<<F2 * DIM / 4 / 256, 256, 0, stream>>>(w13, w13p);
  conv_w2<<<DIM * HID / 4 / 256, 256, 0, stream>>>(w2, w2b);

  const int mtiles1 = Tc / 256;
  const int panel1 = mtiles1 < 8 ? mtiles1 : 8;   // Mtiles is a power of 2
  for (int t0 = 0; t0 < TTOT; t0 += Tc) {
    quant_x<<<Tc, 256, 0, stream>>>(x + (size_t)t0 * DIM, q1, s1);
    gemm8<1, F2, DIM, F2 / 256><<<(Tc / 256) * (F2 / 256), 512, 0, stream>>>(
        q1, w13p, s1, gated, panel1);
    gate_nq<<<Tc, 256, 0, stream>>>(gated, nw, q2f + (size_t)t0 * HID, s2f + t0);
  }
  gemm8<0, DIM, HID, DIM / 256><<<(TTOT / 256) * (DIM / 256), 512, 0, stream>>>(
      q2f, w2b, s2f, out, 8);
}

// Round 16
// 553.987 us; speedup vs baseline: 1.7926x; 1.7926x over previous
//
#include <hip/hip_runtime.h>

typedef unsigned short u16;
typedef __attribute__((ext_vector_type(8))) short short8;
typedef __attribute__((ext_vector_type(4))) float f32x4;
typedef __attribute__((ext_vector_type(4))) u16 ushort4v;
typedef __attribute__((ext_vector_type(8))) u16 ushort8v;

#define DIM 2048
#define HID 5632
#define F2  11264
#define TTOT 8192

#define GLD(g, l) __builtin_amdgcn_global_load_lds(                       \
    (const __attribute__((address_space(1))) void*)(g),                   \
    (__attribute__((address_space(3))) void*)(l), 16, 0, 0)

__device__ __forceinline__ u16 f2bf(float f) {
  unsigned int u = __builtin_bit_cast(unsigned int, f);
  u += 0x7FFFu + ((u >> 16) & 1u);   // round-to-nearest-even (finite values)
  return (u16)(u >> 16);
}

// ---- fused weight conversion (one dispatch):
// part 1: w13 fp32 -> bf16, rows PERMUTED so (x1,x3) pairs are 16-col groups:
//   new row r: b=r>>5, i=r&31; orig = i<16 ? b*16+i : HID+b*16+(i-16)
// part 2: w2 fp32 -> bf16 linear.
__global__ __launch_bounds__(256) void conv_all(const float* __restrict__ w13,
                                                const float* __restrict__ w2,
                                                u16* __restrict__ o13,
                                                u16* __restrict__ o2) {
  int idx = blockIdx.x * 256 + threadIdx.x;
  if (idx < F2 * DIM / 4) {
    int rnew = idx >> 9;                             // DIM/4 = 512 float4/row
    int dc = (idx & 511) << 2;
    int b = rnew >> 5, ii = rnew & 31;
    int orig = (ii < 16) ? (b * 16 + ii) : (HID + b * 16 + (ii - 16));
    float4 v = *reinterpret_cast<const float4*>(w13 + (size_t)orig * DIM + dc);
    ushort4v q = {f2bf(v.x), f2bf(v.y), f2bf(v.z), f2bf(v.w)};
    *reinterpret_cast<ushort4v*>(o13 + (size_t)rnew * DIM + dc) = q;
  } else {
    size_t e = ((size_t)idx - F2 * DIM / 4) * 4;
    float4 v = *reinterpret_cast<const float4*>(w2 + e);
    ushort4v q = {f2bf(v.x), f2bf(v.y), f2bf(v.z), f2bf(v.w)};
    *reinterpret_cast<ushort4v*>(o2 + e) = q;
  }
}

// ---- per-token quant of x: q = rint(x*s) as bf16 (exact ints), scale = max/127
__global__ __launch_bounds__(256) void quant_x(const float* __restrict__ x,
                                               u16* __restrict__ q,
                                               float* __restrict__ scale) {
  const int t = blockIdx.x;
  const float* xr = x + (size_t)t * DIM;
  const int tid = threadIdx.x;
  float4 a = *reinterpret_cast<const float4*>(xr + tid * 8);
  float4 b = *reinterpret_cast<const float4*>(xr + tid * 8 + 4);
  float v[8] = {a.x, a.y, a.z, a.w, b.x, b.y, b.z, b.w};
  float m = 0.f;
#pragma unroll
  for (int i = 0; i < 8; ++i) m = fmaxf(m, fabsf(v[i]));
#pragma unroll
  for (int off = 32; off; off >>= 1) m = fmaxf(m, __shfl_xor(m, off));
  __shared__ float red[4];
  if ((tid & 63) == 0) red[tid >> 6] = m;
  __syncthreads();
  m = fmaxf(fmaxf(red[0], red[1]), fmaxf(red[2], red[3]));
  m = fmaxf(m, 1e-5f);
  float s = 127.0f / m;
  if (tid == 0) scale[t] = m / 127.0f;
  ushort8v o;
#pragma unroll
  for (int i = 0; i < 8; ++i) {
    float r = fminf(fmaxf(rintf(v[i] * s), -128.f), 127.f);
    o[i] = f2bf(r);
  }
  *reinterpret_cast<ushort8v*>(q + (size_t)t * DIM + tid * 8) = o;
}

// ---- gated row -> rmsnorm -> quant (bf16 ints) + scale
__global__ __launch_bounds__(256) void gate_nq(const float* __restrict__ G,
                                               const float* __restrict__ nw,
                                               u16* __restrict__ q2,
                                               float* __restrict__ s2) {
  const int t = blockIdx.x;
  const float* gr = G + (size_t)t * HID;
  const int tid = threadIdx.x;
  float4 vv[6];
  float ss = 0.f, mx = 0.f;
#pragma unroll
  for (int k = 0; k < 6; ++k) {
    int i = tid + k * 256;
    if (i < 1408) {
      float4 v = *reinterpret_cast<const float4*>(gr + i * 4);
      float4 w4 = *reinterpret_cast<const float4*>(nw + i * 4);
      vv[k] = v;
      ss += v.x * v.x + v.y * v.y + v.z * v.z + v.w * v.w;
      mx = fmaxf(mx, fmaxf(fmaxf(fabsf(v.x * w4.x), fabsf(v.y * w4.y)),
                           fmaxf(fabsf(v.z * w4.z), fabsf(v.w * w4.w))));
    }
  }
#pragma unroll
  for (int off = 32; off; off >>= 1) {
    ss += __shfl_xor(ss, off);
    mx = fmaxf(mx, __shfl_xor(mx, off));
  }
  __shared__ float rs[4], rm[4];
  if ((tid & 63) == 0) { rs[tid >> 6] = ss; rm[tid >> 6] = mx; }
  __syncthreads();
  ss = rs[0] + rs[1] + rs[2] + rs[3];
  mx = fmaxf(fmaxf(rm[0], rm[1]), fmaxf(rm[2], rm[3]));
  float rinv = 1.0f / sqrtf(ss * (1.0f / 5632.0f) + 1e-5f);
  float mi = fmaxf(mx * rinv, 1e-5f);
  float s = 127.0f / mi;
  if (tid == 0) s2[t] = mi / 127.0f;
  float fs = rinv * s;
#pragma unroll
  for (int k = 0; k < 6; ++k) {
    int i = tid + k * 256;
    if (i < 1408) {
      float4 v = vv[k];
      float4 w4 = *reinterpret_cast<const float4*>(nw + i * 4);
      ushort4v o;
      o.x = f2bf(fminf(fmaxf(rintf(v.x * w4.x * fs), -128.f), 127.f));
      o.y = f2bf(fminf(fmaxf(rintf(v.y * w4.y * fs), -128.f), 127.f));
      o.z = f2bf(fminf(fmaxf(rintf(v.z * w4.z * fs), -128.f), 127.f));
      o.w = f2bf(fminf(fmaxf(rintf(v.w * w4.w * fs), -128.f), 127.f));
      *reinterpret_cast<ushort4v*>(q2 + (size_t)t * HID + i * 4) = o;
    }
  }
}

// ============================================================================
// 256x256 GEMM: r14 fine interleave (quadrant phases, cross-phase frag reuse,
// reads/phase 12/4/8/0) with r7 barrier discipline: ONE barrier per phase
// (pre-MFMA barrier + manual lgkm(0) drains DELETED -- compiler emits
// fine-grained lgkmcnt per MFMA operand, so the first MFMA starts after its
// 2 reads, not after all 12).
// Hazard audit (1 barrier/phase): a wave reaching a phase-end barrier has
// executed its MFMAs, which required its reads drained -> barrier implies
// all waves' reads of that phase complete. Every stage targets a region whose
// readers are in EARLIER phases (>=1 barrier separation):
//   ph1 stage B-kk1[u+1]->db^1 (tile-u reads are all in db);
//   ph2 stage A-kk1[u+1]->db^1;
//   ph3 stage B-kk0[u+2]->db[1][0]: read by ph1/ph2 (b0k0/b1k0), 1 barrier ago;
//   ph4 stage A-kk0[u+2]->db[0][0]: read by ph1/ph3 (a0k0/a1k0), 1 barrier ago.
// Residency: vmcnt(4)@ph4 drains kk0[u+1]+kk1[u+1] (everything older than the
// 4 newest = kk0[u+2]) before ph4's end barrier -> tile u+1's readers safe.
// Tail: ph4(NT-2) vmcnt(0); tile NT-1 stage-free. Per-acc K order unchanged
// -> bit-identical output.
// LDS 128KB: [db][A/B][kk][256 rows][32 u16]; chunk slot q^((r>>1)&3)
// (both-sides permutation; measured 0 bank conflicts). 512 thr = 8 waves
// (2M x 4N); per-wave 128x64. PANEL supertiling kept (FETCH 383->145 MB).
// GATE=1: gated epilogue over interleaved-w13 n-pairs, C is [M,N/2].
// ============================================================================
template <int GATE, int N, int K, int Ntiles>
__global__ __launch_bounds__(512, 2) void gemm8(
    const u16* __restrict__ A, const u16* __restrict__ B,
    const float* __restrict__ rowscale, float* __restrict__ C, int panel) {
  __shared__ __attribute__((aligned(16))) u16 lds[2][2][2][256 * 32];
  constexpr int NT = K >> 6;            // even: 32 (K=2048), 88 (K=5632)
  const int nwg = gridDim.x;
  const int orig = blockIdx.x;
  const int qq = nwg >> 3, rr = nwg & 7, xcd = orig & 7, sidx = orig >> 3;
  const int wg = (xcd < rr ? xcd * (qq + 1) : rr * (qq + 1) + (xcd - rr) * qq) + sidx;
  const int stripe = panel * Ntiles;
  const int mt = (wg / stripe) * panel + (wg % panel);
  const int nt = (wg % stripe) / panel;

  const int tid = threadIdx.x;
  const int wid = tid >> 6, lane = tid & 63;
  const int wm = wid >> 2, wn = wid & 3;
  const int c16 = lane & 15, q4 = lane >> 4;
  const int rA_base = wm * 128 + c16;
  const int rB_base = wn * 64 + c16;
  const int caf = (q4 ^ ((lane >> 1) & 3)) << 3;  // chunk slot q4^((row>>1)&3)

  // staging: row = tid>>2 (4 lanes/row, 64-B contiguous global segments),
  // source chunk = (tid&3) ^ ((row>>1)&3)  [inverse of the slot permutation]
  const int sr = tid >> 2;
  const int scol = ((tid & 3) ^ ((tid >> 3) & 3)) << 3;
  const u16* Ar = A + ((size_t)mt * 256 + sr) * K + scol;
  const u16* Br = B + ((size_t)nt * 256 + sr) * K + scol;
  constexpr size_t rstep = (size_t)128 * K;

  f32x4 acc[8][4];
#pragma unroll
  for (int m = 0; m < 8; ++m)
#pragma unroll
    for (int n = 0; n < 4; ++n) acc[m][n] = f32x4{0.f, 0.f, 0.f, 0.f};

#define STAGE(MAT, KK, T, BUF)                                                \
  {                                                                           \
    const u16* g = ((MAT) ? Br : Ar) + (T) * 64 + (KK) * 32;                  \
    u16* l = &lds[BUF][MAT][KK][wid << 9];                                    \
    GLD(g, l);                                                                \
    GLD(g + rstep, l + 4096);                                                 \
  }
#define LDA(DB, KK, MH, AF)                                                   \
  _Pragma("unroll") for (int m = 0; m < 4; ++m)                               \
      AF[m] = *reinterpret_cast<const short8*>(                               \
          &lds[DB][0][KK][(rA_base + ((MH) * 4 + m) * 16) * 32 + caf]);
#define LDB2(DB, KK, NH, BF)                                                  \
  _Pragma("unroll") for (int n = 0; n < 2; ++n)                               \
      BF[n] = *reinterpret_cast<const short8*>(                               \
          &lds[DB][1][KK][(rB_base + ((NH) * 2 + n) * 16) * 32 + caf]);
// One C-quadrant, full K=64: kk0 sweep then kk1 sweep (per-acc order: kk0,kk1)
#define MFMAQ(AK0, AK1, BK0, BK1, MOFS, NOFS)                                 \
  __builtin_amdgcn_s_setprio(1);                                              \
  _Pragma("unroll") for (int m = 0; m < 4; ++m)                               \
      _Pragma("unroll") for (int n = 0; n < 2; ++n)                           \
          acc[(MOFS) + m][(NOFS) + n] = __builtin_amdgcn_mfma_f32_16x16x32_bf16( \
              AK0[m], BK0[n], acc[(MOFS) + m][(NOFS) + n], 0, 0, 0);          \
  _Pragma("unroll") for (int m = 0; m < 4; ++m)                               \
      _Pragma("unroll") for (int n = 0; n < 2; ++n)                           \
          acc[(MOFS) + m][(NOFS) + n] = __builtin_amdgcn_mfma_f32_16x16x32_bf16( \
              AK1[m], BK1[n], acc[(MOFS) + m][(NOFS) + n], 0, 0, 0);          \
  __builtin_amdgcn_s_setprio(0);                                              \
  __builtin_amdgcn_sched_barrier(0);
#define BARR asm volatile("s_barrier" ::: "memory")
#define VMC(NN) asm volatile("s_waitcnt vmcnt(" #NN ")" ::: "memory")
#define NOPW do {} while (0)

#define KT4(DB, U, STG12, STG34, WB)                                          \
  {                                                                           \
    short8 a0k0[4], a0k1[4], a1k0[4], a1k1[4];                                \
    short8 b0k0[2], b0k1[2], b1k0[2], b1k1[2];                                \
    /* ph1: Q(0,0); reads 12 */                                               \
    LDA(DB, 0, 0, a0k0) LDA(DB, 1, 0, a0k1)                                   \
    LDB2(DB, 0, 0, b0k0) LDB2(DB, 1, 0, b0k1)                                 \
    if (STG12) { STAGE(1, 1, (U) + 1, (DB) ^ 1) }                             \
    MFMAQ(a0k0, a0k1, b0k0, b0k1, 0, 0)                                       \
    BARR;                                                                     \
    /* ph2: Q(0,1); reads 4 (A-mh0 reused) */                                 \
    LDB2(DB, 0, 1, b1k0) LDB2(DB, 1, 1, b1k1)                                 \
    if (STG12) { STAGE(0, 1, (U) + 1, (DB) ^ 1) }                             \
    MFMAQ(a0k0, a0k1, b1k0, b1k1, 0, 2)                                       \
    BARR;                                                                     \
    /* ph3: Q(1,0); reads 8 (B-nh0 reused) */                                 \
    LDA(DB, 0, 1, a1k0) LDA(DB, 1, 1, a1k1)                                   \
    if (STG34) { STAGE(1, 0, (U) + 2, DB) }                                   \
    MFMAQ(a1k0, a1k1, b0k0, b0k1, 4, 0)                                       \
    BARR;                                                                     \
    /* ph4: Q(1,1); no reads */                                               \
    if (STG34) { STAGE(0, 0, (U) + 2, DB) }                                   \
    MFMAQ(a1k0, a1k1, b1k0, b1k1, 4, 2)                                       \
    WB; BARR;                                                                 \
  }

  // prologue: tile0 (kk0,kk1)->buf0 (8 GLDs), kk0[1]->buf1 (4 GLDs);
  // vmcnt(4) -> tile0 resident (8 oldest complete).
  STAGE(1, 0, 0, 0) STAGE(0, 0, 0, 0) STAGE(1, 1, 0, 0) STAGE(0, 1, 0, 0)
  STAGE(1, 0, 1, 1) STAGE(0, 0, 1, 1)
  VMC(4);
  BARR;

#pragma unroll 1
  for (int u = 0; u < NT - 2; u += 2) {
    KT4(0, u, 1, 1, VMC(4))
    KT4(1, u + 1, 1, 1, VMC(4))
  }
  // tail: tile NT-2 stages kk1[NT-1] (ph1/2) then drains; tile NT-1 stage-free.
  KT4(0, NT - 2, 1, 0, VMC(0))
  KT4(1, NT - 1, 0, 0, NOPW)

  // ---- epilogue
  const int mbase0 = mt * 256 + wm * 128;
  if constexpr (GATE == 0) {
#pragma unroll
    for (int m = 0; m < 8; ++m) {
#pragma unroll
      for (int j = 0; j < 4; ++j) {
        const int row = mbase0 + m * 16 + q4 * 4 + j;
        const float sc = rowscale[row];
        float* crow = C + (size_t)row * N + nt * 256 + wn * 64 + c16;
#pragma unroll
        for (int n = 0; n < 4; ++n) crow[n * 16] = acc[m][n][j] * sc;
      }
    }
  } else {
    constexpr int H = N >> 1;
    const int gbase = (nt * 256 + wn * 64) >> 1;
#pragma unroll
    for (int m = 0; m < 8; ++m) {
#pragma unroll
      for (int j = 0; j < 4; ++j) {
        const int row = mbase0 + m * 16 + q4 * 4 + j;
        const float sc = rowscale[row];
        const float s3 = sc * sc * sc;
        float* grow = C + (size_t)row * H + gbase + c16;
#pragma unroll
        for (int p = 0; p < 2; ++p) {
          float a1 = acc[m][2 * p][j];
          float a3 = acc[m][2 * p + 1][j];
          float rl = fmaxf(a1, 0.f);
          grow[p * 16] = rl * rl * a3 * s3;
        }
      }
    }
  }
}

extern "C" void kernel_launch(void* const* d_in, const int* in_sizes, int n_in,
                              void* d_out, int out_size, void* d_ws, size_t ws_size,
                              hipStream_t stream) {
  const float* x = (const float*)d_in[0];
  const float* w13 = (const float*)d_in[1];
  const float* w2 = (const float*)d_in[2];
  const float* nw = (const float*)d_in[3];
  float* out = (float*)d_out;

  char* p = (char*)d_ws;
  u16* w13p = (u16*)p; p += (size_t)F2 * DIM * 2;
  u16* w2b = (u16*)p;  p += (size_t)DIM * HID * 2;
  u16* q2f = (u16*)p;  p += (size_t)TTOT * HID * 2;
  float* s2f = (float*)p; p += (size_t)TTOT * 4;
  const size_t fixed = (size_t)F2 * DIM * 2 + (size_t)DIM * HID * 2 +
                       (size_t)TTOT * HID * 2 + (size_t)TTOT * 4;
  const size_t perTok = (size_t)DIM * 2 + (size_t)HID * 4 + 8;
  int Tc = TTOT;
  while (Tc > 256 && fixed + (size_t)Tc * perTok > ws_size) Tc >>= 1;
  u16* q1 = (u16*)p;        p += (size_t)Tc * DIM * 2;
  float* gated = (float*)p; p += (size_t)Tc * HID * 4;
  float* s1 = (float*)p;

  conv_all<<<(F2 * DIM / 4 + DIM * HID / 4) / 256, 256, 0, stream>>>(
      w13, w2, w13p, w2b);

  const int mtiles1 = Tc / 256;
  const int panel1 = mtiles1 < 8 ? mtiles1 : 8;   // Mtiles is a power of 2
  for (int t0 = 0; t0 < TTOT; t0 += Tc) {
    quant_x<<<Tc, 256, 0, stream>>>(x + (size_t)t0 * DIM, q1, s1);
    gemm8<1, F2, DIM, F2 / 256><<<(Tc / 256) * (F2 / 256), 512, 0, stream>>>(
        q1, w13p, s1, gated, panel1);
    gate_nq<<<Tc, 256, 0, stream>>>(gated, nw, q2f + (size_t)t0 * HID, s2f + t0);
  }
  gemm8<0, DIM, HID, DIM / 256><<<(TTOT / 256) * (DIM / 256), 512, 0, stream>>>(
      q2f, w2b, s2f, out, 8);
}